// Round 5
// baseline (2258.734 us; speedup 1.0000x reference)
//
#include <hip/hip_runtime.h>

#define ALPHA 0.2f
__device__ __forceinline__ float lrelu_f(float x){ return x>0.f ? x : ALPHA*x; }
__device__ __forceinline__ float4 zero4(){ float4 z; z.x=z.y=z.z=z.w=0.f; return z; }

// ============ Encoder: 3x3 s2 SAME conv (pad lo=0,hi=1), TO chans x TX pixels per thread ====
template<int H,int W,int CIN,int COUT,int TO,int TX,bool LRELU>
__global__ __launch_bounds__(256) void conv3x3_s2_k(const float* __restrict__ in,
    const float* __restrict__ w, const float* __restrict__ bias, float* __restrict__ out,
    int total){
  constexpr int Ho=H/2, Wo=W/2, OB=COUT/TO, XB=Wo/TX;
  int t = blockIdx.x*256 + threadIdx.x;
  if (t >= total) return;
  int ob = t % OB; int p = t/OB;
  int xb = p % XB; p /= XB;
  int y  = p % Ho; int n = p/Ho;
  int x0 = xb*TX;

  float acc[TX][TO];
  #pragma unroll
  for (int j4=0;j4<TO/4;j4++){
    float4 bv = *(const float4*)(bias + ob*TO + j4*4);
    #pragma unroll
    for (int px=0;px<TX;px++){
      acc[px][j4*4+0]=bv.x; acc[px][j4*4+1]=bv.y;
      acc[px][j4*4+2]=bv.z; acc[px][j4*4+3]=bv.w;
    }
  }

  #pragma unroll
  for (int ky=0;ky<3;ky++){
    int iy = 2*y + ky;
    if (iy >= H) continue;
    const float* row = in + ((size_t)n*H + iy)*(size_t)(W*CIN);
    #pragma unroll
    for (int kx=0;kx<3;kx++){
      const float* wp = w + ((ky*3+kx)*CIN)*COUT + ob*TO;
      const float* ipx[TX]; bool okx[TX];
      #pragma unroll
      for (int px=0;px<TX;px++){
        int ix = 2*(x0+px)+kx;
        okx[px] = (ix < W);
        ipx[px] = row + (size_t)(okx[px] ? ix : (W-1))*CIN;
      }
      if constexpr (CIN==3){
        #pragma unroll
        for (int ci=0;ci<3;ci++){
          float4 wv[TO/4];
          #pragma unroll
          for (int j4=0;j4<TO/4;j4++) wv[j4] = *(const float4*)(wp + ci*COUT + j4*4);
          #pragma unroll
          for (int px=0;px<TX;px++){
            float v = okx[px] ? ipx[px][ci] : 0.f;
            #pragma unroll
            for (int j4=0;j4<TO/4;j4++){
              acc[px][j4*4+0] += v*wv[j4].x; acc[px][j4*4+1] += v*wv[j4].y;
              acc[px][j4*4+2] += v*wv[j4].z; acc[px][j4*4+3] += v*wv[j4].w;
            }
          }
        }
      } else {
        for (int c=0;c<CIN;c+=4){
          float4 wv[4][TO/4];
          #pragma unroll
          for (int ci=0;ci<4;ci++)
            #pragma unroll
            for (int j4=0;j4<TO/4;j4++)
              wv[ci][j4] = *(const float4*)(wp + (c+ci)*COUT + j4*4);
          #pragma unroll
          for (int px=0;px<TX;px++){
            float4 vv = *(const float4*)(ipx[px]+c);
            if (!okx[px]) vv = zero4();
            float vc[4] = {vv.x, vv.y, vv.z, vv.w};
            #pragma unroll
            for (int ci=0;ci<4;ci++)
              #pragma unroll
              for (int j4=0;j4<TO/4;j4++){
                acc[px][j4*4+0] += vc[ci]*wv[ci][j4].x;
                acc[px][j4*4+1] += vc[ci]*wv[ci][j4].y;
                acc[px][j4*4+2] += vc[ci]*wv[ci][j4].z;
                acc[px][j4*4+3] += vc[ci]*wv[ci][j4].w;
              }
          }
        }
      }
    }
  }
  #pragma unroll
  for (int px=0;px<TX;px++){
    float* op = out + ((size_t)((n*Ho+y)*Wo + x0+px))*COUT + ob*TO;
    #pragma unroll
    for (int j4=0;j4<TO/4;j4++){
      float4 r;
      r.x = LRELU?lrelu_f(acc[px][j4*4+0]):acc[px][j4*4+0];
      r.y = LRELU?lrelu_f(acc[px][j4*4+1]):acc[px][j4*4+1];
      r.z = LRELU?lrelu_f(acc[px][j4*4+2]):acc[px][j4*4+2];
      r.w = LRELU?lrelu_f(acc[px][j4*4+3]):acc[px][j4*4+3];
      *(float4*)(op+j4*4) = r;
    }
  }
}

// ============ Fused enc4 (1x1 conv 64->32) + vector-quantize ============
template<int CIN,int D,int K>
__global__ __launch_bounds__(256) void enc4_vq_k(const float* __restrict__ in,
    const float* __restrict__ w, const float* __restrict__ bias,
    const float* __restrict__ cb, float* __restrict__ q, int npix){
  int i = blockIdx.x*256 + threadIdx.x;
  if (i >= npix) return;
  const float* ip = in + (size_t)i*CIN;
  float z[D];
  #pragma unroll
  for (int d=0; d<D; d++) z[d] = bias[d];
  for (int c=0; c<CIN; c+=4){
    float4 v = *(const float4*)(ip + c);
    #pragma unroll
    for (int d=0; d<D; d++){
      z[d] += v.x * w[(c+0)*D + d];
      z[d] += v.y * w[(c+1)*D + d];
      z[d] += v.z * w[(c+2)*D + d];
      z[d] += v.w * w[(c+3)*D + d];
    }
  }
  float z2 = 0.f;
  #pragma unroll
  for (int d=0; d<D; d++) z2 += z[d]*z[d];
  float best = 3.4e38f; int bi = 0;
  for (int k=0; k<K; k++){
    float e2 = 0.f, dot = 0.f;
    #pragma unroll
    for (int d=0; d<D; d++){
      float cv = cb[d*K + k];
      e2  += cv*cv;
      dot += z[d]*cv;
    }
    float dist = z2 + e2 - 2.f*dot;
    if (dist < best){ best = dist; bi = k; }   // strict < == first-min (jnp.argmin)
  }
  float* qp = q + (size_t)i*D;
  #pragma unroll
  for (int d=0; d<D; d++) qp[d] = cb[d*K + bi];
}

// ===== Decoder conv_transpose 3x3 s2 SAME (JAX, unflipped): full 2x2 parity group/thread ====
// Tap (ky,kx) feeds parity (py=ky&1, px=kx&1); input offset dy=-1 iff ky==0, dx=-1 iff kx==0.
// Thread: TX group-columns x 2x2 parities x TO channels. Input rows {yy-1,yy}, cols x0-1..x0+TX-1
// each loaded once per c-quad and reused by all 9 taps.
template<int H,int W,int CIN,int COUT,int TO,int TX,bool LRELU>
__global__ __launch_bounds__(256) void deconv3x3_s2_g_k(const float* __restrict__ in,
    const float* __restrict__ w, const float* __restrict__ bias, float* __restrict__ out,
    int total){
  constexpr int Ho=2*H, Wo=2*W, OB=COUT/TO, XB=W/TX;
  int t = blockIdx.x*256 + threadIdx.x;
  if (t >= total) return;
  int ob = t % OB; int p = t/OB;
  int xb = p % XB; p /= XB;
  int yy = p % H;  int n = p/H;
  int x0 = xb*TX;

  float acc[TX][2][2][TO];
  #pragma unroll
  for (int j4=0;j4<TO/4;j4++){
    float4 bv = *(const float4*)(bias + ob*TO + j4*4);
    #pragma unroll
    for (int g=0;g<TX;g++)
      #pragma unroll
      for (int py=0;py<2;py++)
        #pragma unroll
        for (int px=0;px<2;px++){
          acc[g][py][px][j4*4+0]=bv.x; acc[g][py][px][j4*4+1]=bv.y;
          acc[g][py][px][j4*4+2]=bv.z; acc[g][py][px][j4*4+3]=bv.w;
        }
  }

  const float* row1 = in + ((size_t)n*H + yy)*(size_t)(W*CIN);
  const float* row0 = row1 - (size_t)(W*CIN);
  const bool hasTop = (yy > 0);   // wave-uniform (OB*XB multiple of 64)

  for (int c=0;c<CIN;c+=4){
    float4 iv[2][TX+1];                 // [row 0=yy-1,1=yy][col j: ix = x0-1+j]
    #pragma unroll
    for (int j=0;j<=TX;j++){
      int ix = x0 - 1 + j;
      bool okc = (ix >= 0);
      size_t off = (size_t)(okc ? ix : 0)*CIN + c;
      float4 a0 = hasTop ? *(const float4*)(row0 + off) : zero4();
      float4 a1 = *(const float4*)(row1 + off);
      if (!okc){ a0 = zero4(); a1 = zero4(); }
      iv[0][j] = a0; iv[1][j] = a1;
    }
    #pragma unroll
    for (int ky=0;ky<3;ky++){
      const int py = ky & 1;
      const int r  = (ky==0) ? 0 : 1;
      #pragma unroll
      for (int kx=0;kx<3;kx++){
        const int px = kx & 1;
        const int jo = (kx==0) ? 0 : 1;
        const float* wp = w + ((size_t)((ky*3+kx)*CIN + c))*COUT + ob*TO;
        float4 wv[4][TO/4];
        #pragma unroll
        for (int ci=0;ci<4;ci++)
          #pragma unroll
          for (int j4=0;j4<TO/4;j4++)
            wv[ci][j4] = *(const float4*)(wp + ci*COUT + j4*4);
        #pragma unroll
        for (int g=0;g<TX;g++){
          float4 v = iv[r][g+jo];
          float vc[4] = {v.x, v.y, v.z, v.w};
          #pragma unroll
          for (int ci=0;ci<4;ci++)
            #pragma unroll
            for (int j4=0;j4<TO/4;j4++){
              acc[g][py][px][j4*4+0] += vc[ci]*wv[ci][j4].x;
              acc[g][py][px][j4*4+1] += vc[ci]*wv[ci][j4].y;
              acc[g][py][px][j4*4+2] += vc[ci]*wv[ci][j4].z;
              acc[g][py][px][j4*4+3] += vc[ci]*wv[ci][j4].w;
            }
        }
      }
    }
  }

  #pragma unroll
  for (int g=0;g<TX;g++){
    #pragma unroll
    for (int py=0;py<2;py++){
      int yo = 2*yy + py;
      #pragma unroll
      for (int px=0;px<2;px++){
        int xo = 2*(x0+g) + px;
        float* op = out + ((size_t)((n*Ho+yo)*Wo + xo))*COUT + ob*TO;
        #pragma unroll
        for (int j4=0;j4<TO/4;j4++){
          float4 rr;
          rr.x = LRELU?lrelu_f(acc[g][py][px][j4*4+0]):acc[g][py][px][j4*4+0];
          rr.y = LRELU?lrelu_f(acc[g][py][px][j4*4+1]):acc[g][py][px][j4*4+1];
          rr.z = LRELU?lrelu_f(acc[g][py][px][j4*4+2]):acc[g][py][px][j4*4+2];
          rr.w = LRELU?lrelu_f(acc[g][py][px][j4*4+3]):acc[g][py][px][j4*4+3];
          *(float4*)(op+j4*4) = rr;
        }
      }
    }
  }
}

// ============ dec4: s1 deconv == 3x3 pad-1 conv, Cout=1; TX outputs share input columns ====
template<int H,int W,int CIN,int TX>
__global__ __launch_bounds__(256) void conv3x3_s1_co1_k(const float* __restrict__ in,
    const float* __restrict__ w, const float* __restrict__ bias, float* __restrict__ out,
    int total){
  constexpr int XB = W/TX;
  int t = blockIdx.x*256 + threadIdx.x;
  if (t >= total) return;
  int xb = t % XB; int p = t/XB;
  int y  = p % H;  int n = p/H;
  int x0 = xb*TX;

  float acc[TX];
  #pragma unroll
  for (int px=0;px<TX;px++) acc[px] = bias[0];

  #pragma unroll
  for (int ky=0;ky<3;ky++){
    int iy = y + ky - 1;
    if (iy < 0 || iy >= H) continue;
    const float* row = in + ((size_t)n*H + iy)*(size_t)(W*CIN);
    const float* wk  = w + (ky*3)*CIN;
    for (int c=0;c<CIN;c+=4){
      float4 wv[3];
      #pragma unroll
      for (int kx=0;kx<3;kx++) wv[kx] = *(const float4*)(wk + kx*CIN + c);
      #pragma unroll
      for (int j=0;j<TX+2;j++){
        int ix = x0 + j - 1;
        bool ok = (ix >= 0 && ix < W);
        float4 v = *(const float4*)(row + (size_t)(ok ? ix : 0)*CIN + c);
        if (!ok) v = zero4();
        #pragma unroll
        for (int kx=0;kx<3;kx++){
          int px = j - kx;
          if (px >= 0 && px < TX){
            acc[px] += v.x*wv[kx].x + v.y*wv[kx].y + v.z*wv[kx].z + v.w*wv[kx].w;
          }
        }
      }
    }
  }
  float* op = out + (size_t)(n*H + y)*W + x0;
  if constexpr (TX == 4){
    float4 r; r.x=acc[0]; r.y=acc[1]; r.z=acc[2]; r.w=acc[3];
    *(float4*)op = r;
  } else {
    #pragma unroll
    for (int px=0;px<TX;px++) op[px] = acc[px];
  }
}

extern "C" void kernel_launch(void* const* d_in, const int* in_sizes, int n_in,
                              void* d_out, int out_size, void* d_ws, size_t ws_size,
                              hipStream_t stream) {
  const float* x   = (const float*)d_in[0];
  const float* e1w = (const float*)d_in[1];  const float* e1b = (const float*)d_in[2];
  const float* e2w = (const float*)d_in[3];  const float* e2b = (const float*)d_in[4];
  const float* e3w = (const float*)d_in[5];  const float* e3b = (const float*)d_in[6];
  const float* e4w = (const float*)d_in[7];  const float* e4b = (const float*)d_in[8];
  const float* cb  = (const float*)d_in[9];
  const float* d1w = (const float*)d_in[10]; const float* d1b = (const float*)d_in[11];
  const float* d2w = (const float*)d_in[12]; const float* d2b = (const float*)d_in[13];
  const float* d3w = (const float*)d_in[14]; const float* d3b = (const float*)d_in[15];
  const float* d4w = (const float*)d_in[16]; const float* d4b = (const float*)d_in[17];
  float* out = (float*)d_out;

  // Per-image ping-pong: A = max(h1,h3,d1,d3) = 8 MiB/img; B = max(h2,q,d2) = 4 MiB/img.
  const size_t MiB = 1ull << 20;
  int Bc = 32;
  while (Bc > 1 && (size_t)Bc * 12 * MiB > ws_size) Bc >>= 1;

  char* wsb = (char*)d_ws;
  float* A  = (float*)wsb;                              // Bc * 8 MiB
  float* Bf = (float*)(wsb + (size_t)Bc * 8 * MiB);     // Bc * 4 MiB

  for (int n0 = 0; n0 < 32; n0 += Bc) {
    const float* xc = x   + (size_t)n0 * 256*256*3;
    float*      oc  = out + (size_t)n0 * 256*256;

    // enc1: [Bc,256,256,3] -> [Bc,128,128,32]; TO=8(OB=4), TX=2(XB=64)
    int t1 = Bc*128*64*4;
    conv3x3_s2_k<256,256,3,32,8,2,true><<<t1/256,256,0,stream>>>(xc, e1w, e1b, A, t1);
    // enc2: -> [Bc,64,64,64]; TO=8(OB=8), TX=4(XB=16)
    int t2 = Bc*64*16*8;
    conv3x3_s2_k<128,128,32,64,8,4,true><<<t2/256,256,0,stream>>>(A, e2w, e2b, Bf, t2);
    // enc3: -> [Bc,32,32,64]; TO=8(OB=8), TX=4(XB=8)
    int t3 = Bc*32*8*8;
    conv3x3_s2_k<64,64,64,64,8,4,true><<<t3/256,256,0,stream>>>(Bf, e3w, e3b, A, t3);
    // enc4 (1x1, 64->32) + VQ: -> q [Bc,32,32,32]
    int npix = Bc*32*32;
    enc4_vq_k<64,32,64><<<npix/256,256,0,stream>>>(A, e4w, e4b, cb, Bf, npix);
    // dec1: [Bc,32,32,32] -> [Bc,64,64,64]; TO=8(OB=8), TX=2(XB=16)
    int t5 = Bc*32*16*8;
    deconv3x3_s2_g_k<32,32,32,64,8,2,true><<<t5/256,256,0,stream>>>(Bf, d1w, d1b, A, t5);
    // dec2: -> [Bc,128,128,64]; TO=8(OB=8), TX=2(XB=32)
    int t6 = Bc*64*32*8;
    deconv3x3_s2_g_k<64,64,64,64,8,2,true><<<t6/256,256,0,stream>>>(A, d2w, d2b, Bf, t6);
    // dec3: -> [Bc,256,256,32]; TO=8(OB=4), TX=2(XB=64)
    int t7 = Bc*128*64*4;
    deconv3x3_s2_g_k<128,128,64,32,8,2,true><<<t7/256,256,0,stream>>>(Bf, d3w, d3b, A, t7);
    // dec4: -> [Bc,256,256,1]; TX=4
    int t8 = Bc*256*64;
    conv3x3_s1_co1_k<256,256,32,4><<<t8/256,256,0,stream>>>(A, d4w, d4b, oc, t8);
  }
}

// Round 6
// 2029.781 us; speedup vs baseline: 1.1128x; 1.1128x over previous
//
#include <hip/hip_runtime.h>

#define ALPHA 0.2f
__device__ __forceinline__ float lrelu_f(float x){ return x>0.f ? x : ALPHA*x; }
__device__ __forceinline__ float4 zero4(){ float4 z; z.x=z.y=z.z=z.w=0.f; return z; }

// ============ Encoder: 3x3 s2 SAME conv (pad lo=0,hi=1), TO chans x TX pixels per thread ====
template<int H,int W,int CIN,int COUT,int TO,int TX,bool LRELU>
__global__ __launch_bounds__(256) void conv3x3_s2_k(const float* __restrict__ in,
    const float* __restrict__ w, const float* __restrict__ bias, float* __restrict__ out,
    int total){
  constexpr int Ho=H/2, Wo=W/2, OB=COUT/TO, XB=Wo/TX;
  int t = blockIdx.x*256 + threadIdx.x;
  if (t >= total) return;
  int ob = t % OB; int p = t/OB;
  int xb = p % XB; p /= XB;
  int y  = p % Ho; int n = p/Ho;
  int x0 = xb*TX;

  float acc[TX][TO];
  #pragma unroll
  for (int j4=0;j4<TO/4;j4++){
    float4 bv = *(const float4*)(bias + ob*TO + j4*4);
    #pragma unroll
    for (int px=0;px<TX;px++){
      acc[px][j4*4+0]=bv.x; acc[px][j4*4+1]=bv.y;
      acc[px][j4*4+2]=bv.z; acc[px][j4*4+3]=bv.w;
    }
  }

  #pragma unroll
  for (int ky=0;ky<3;ky++){
    int iy = 2*y + ky;
    if (iy >= H) continue;
    const float* row = in + ((size_t)n*H + iy)*(size_t)(W*CIN);
    #pragma unroll
    for (int kx=0;kx<3;kx++){
      const float* wp = w + ((ky*3+kx)*CIN)*COUT + ob*TO;
      const float* ipx[TX]; bool okx[TX];
      #pragma unroll
      for (int px=0;px<TX;px++){
        int ix = 2*(x0+px)+kx;
        okx[px] = (ix < W);
        ipx[px] = row + (size_t)(okx[px] ? ix : (W-1))*CIN;
      }
      if constexpr (CIN==3){
        #pragma unroll
        for (int ci=0;ci<3;ci++){
          float4 wv[TO/4];
          #pragma unroll
          for (int j4=0;j4<TO/4;j4++) wv[j4] = *(const float4*)(wp + ci*COUT + j4*4);
          #pragma unroll
          for (int px=0;px<TX;px++){
            float v = okx[px] ? ipx[px][ci] : 0.f;
            #pragma unroll
            for (int j4=0;j4<TO/4;j4++){
              acc[px][j4*4+0] += v*wv[j4].x; acc[px][j4*4+1] += v*wv[j4].y;
              acc[px][j4*4+2] += v*wv[j4].z; acc[px][j4*4+3] += v*wv[j4].w;
            }
          }
        }
      } else {
        for (int c=0;c<CIN;c+=4){
          float4 wv[4][TO/4];
          #pragma unroll
          for (int ci=0;ci<4;ci++)
            #pragma unroll
            for (int j4=0;j4<TO/4;j4++)
              wv[ci][j4] = *(const float4*)(wp + (c+ci)*COUT + j4*4);
          #pragma unroll
          for (int px=0;px<TX;px++){
            float4 vv = *(const float4*)(ipx[px]+c);
            if (!okx[px]) vv = zero4();
            float vc[4] = {vv.x, vv.y, vv.z, vv.w};
            #pragma unroll
            for (int ci=0;ci<4;ci++)
              #pragma unroll
              for (int j4=0;j4<TO/4;j4++){
                acc[px][j4*4+0] += vc[ci]*wv[ci][j4].x;
                acc[px][j4*4+1] += vc[ci]*wv[ci][j4].y;
                acc[px][j4*4+2] += vc[ci]*wv[ci][j4].z;
                acc[px][j4*4+3] += vc[ci]*wv[ci][j4].w;
              }
          }
        }
      }
    }
  }
  #pragma unroll
  for (int px=0;px<TX;px++){
    float* op = out + ((size_t)((n*Ho+y)*Wo + x0+px))*COUT + ob*TO;
    #pragma unroll
    for (int j4=0;j4<TO/4;j4++){
      float4 r;
      r.x = LRELU?lrelu_f(acc[px][j4*4+0]):acc[px][j4*4+0];
      r.y = LRELU?lrelu_f(acc[px][j4*4+1]):acc[px][j4*4+1];
      r.z = LRELU?lrelu_f(acc[px][j4*4+2]):acc[px][j4*4+2];
      r.w = LRELU?lrelu_f(acc[px][j4*4+3]):acc[px][j4*4+3];
      *(float4*)(op+j4*4) = r;
    }
  }
}

// ============ Fused enc4 (1x1 conv 64->32) + vector-quantize ============
template<int CIN,int D,int K>
__global__ __launch_bounds__(256) void enc4_vq_k(const float* __restrict__ in,
    const float* __restrict__ w, const float* __restrict__ bias,
    const float* __restrict__ cb, float* __restrict__ q, int npix){
  int i = blockIdx.x*256 + threadIdx.x;
  if (i >= npix) return;
  const float* ip = in + (size_t)i*CIN;
  float z[D];
  #pragma unroll
  for (int d=0; d<D; d++) z[d] = bias[d];
  for (int c=0; c<CIN; c+=4){
    float4 v = *(const float4*)(ip + c);
    #pragma unroll
    for (int d=0; d<D; d++){
      z[d] += v.x * w[(c+0)*D + d];
      z[d] += v.y * w[(c+1)*D + d];
      z[d] += v.z * w[(c+2)*D + d];
      z[d] += v.w * w[(c+3)*D + d];
    }
  }
  float z2 = 0.f;
  #pragma unroll
  for (int d=0; d<D; d++) z2 += z[d]*z[d];
  float best = 3.4e38f; int bi = 0;
  for (int k=0; k<K; k++){
    float e2 = 0.f, dot = 0.f;
    #pragma unroll
    for (int d=0; d<D; d++){
      float cv = cb[d*K + k];
      e2  += cv*cv;
      dot += z[d]*cv;
    }
    float dist = z2 + e2 - 2.f*dot;
    if (dist < best){ best = dist; bi = k; }   // strict < == first-min (jnp.argmin)
  }
  float* qp = q + (size_t)i*D;
  #pragma unroll
  for (int d=0; d<D; d++) qp[d] = cb[d*K + bi];
}

// ===== Decoder conv_transpose 3x3 s2 SAME (JAX, unflipped): full 2x2 parity group/thread ====
// Tap (ky,kx) feeds parity (py=ky&1, px=kx&1); input row r=0 (yy-1) iff ky==0, col off iff kx==0.
// Register-economical: weights staged one ci at a time; __launch_bounds__(256,4) caps VGPR @128
// so the 64-float accumulator does NOT spill (round-5 lesson: VGPR_Count=72 => spilled acc).
template<int H,int W,int CIN,int COUT,int TO,int TX,bool LRELU>
__global__ __launch_bounds__(256,4) void deconv3x3_s2_g_k(const float* __restrict__ in,
    const float* __restrict__ w, const float* __restrict__ bias, float* __restrict__ out,
    int total){
  constexpr int Ho=2*H, Wo=2*W, OB=COUT/TO, XB=W/TX;
  // XCD-aware swizzle: give each of the 8 XCDs a contiguous spatial range (grid % 8 == 0).
  int nblk = gridDim.x;
  int b = blockIdx.x;
  int bs = (nblk >= 8) ? ((b & 7) * (nblk >> 3) + (b >> 3)) : b;
  int t = bs*256 + threadIdx.x;
  if (t >= total) return;
  int ob = t % OB; int p = t/OB;
  int xb = p % XB; p /= XB;
  int yy = p % H;  int n = p/H;
  int x0 = xb*TX;

  float acc[TX][2][2][TO];
  #pragma unroll
  for (int j4=0;j4<TO/4;j4++){
    float4 bv = *(const float4*)(bias + ob*TO + j4*4);
    #pragma unroll
    for (int g=0;g<TX;g++)
      #pragma unroll
      for (int py=0;py<2;py++)
        #pragma unroll
        for (int px=0;px<2;px++){
          acc[g][py][px][j4*4+0]=bv.x; acc[g][py][px][j4*4+1]=bv.y;
          acc[g][py][px][j4*4+2]=bv.z; acc[g][py][px][j4*4+3]=bv.w;
        }
  }

  const float* row1 = in + ((size_t)n*H + yy)*(size_t)(W*CIN);
  const float* row0 = row1 - (size_t)(W*CIN);
  const bool hasTop = (yy > 0);   // wave-uniform (OB*XB multiple of 64)

  for (int c=0;c<CIN;c+=4){
    float4 iv[2][TX+1];                 // [row 0=yy-1,1=yy][col j: ix = x0-1+j]
    #pragma unroll
    for (int j=0;j<=TX;j++){
      int ix = x0 - 1 + j;
      bool okc = (ix >= 0);
      size_t off = (size_t)(okc ? ix : 0)*CIN + c;
      float4 a0 = hasTop ? *(const float4*)(row0 + off) : zero4();
      float4 a1 = *(const float4*)(row1 + off);
      if (!okc){ a0 = zero4(); a1 = zero4(); }
      iv[0][j] = a0; iv[1][j] = a1;
    }
    #pragma unroll
    for (int ky=0;ky<3;ky++){
      const int py = ky & 1;
      const int r  = (ky==0) ? 0 : 1;
      #pragma unroll
      for (int kx=0;kx<3;kx++){
        const int px = kx & 1;
        const int jo = (kx==0) ? 0 : 1;
        const float* wp = w + ((size_t)((ky*3+kx)*CIN + c))*COUT + ob*TO;
        #pragma unroll
        for (int ci=0;ci<4;ci++){
          float4 wv[TO/4];                      // only 8 transient VGPRs staged
          #pragma unroll
          for (int j4=0;j4<TO/4;j4++)
            wv[j4] = *(const float4*)(wp + ci*COUT + j4*4);
          #pragma unroll
          for (int g=0;g<TX;g++){
            float4 v = iv[r][g+jo];
            float vc = (ci==0)?v.x:(ci==1)?v.y:(ci==2)?v.z:v.w;
            #pragma unroll
            for (int j4=0;j4<TO/4;j4++){
              acc[g][py][px][j4*4+0] += vc*wv[j4].x;
              acc[g][py][px][j4*4+1] += vc*wv[j4].y;
              acc[g][py][px][j4*4+2] += vc*wv[j4].z;
              acc[g][py][px][j4*4+3] += vc*wv[j4].w;
            }
          }
        }
      }
    }
  }

  #pragma unroll
  for (int g=0;g<TX;g++){
    #pragma unroll
    for (int py=0;py<2;py++){
      int yo = 2*yy + py;
      #pragma unroll
      for (int px=0;px<2;px++){
        int xo = 2*(x0+g) + px;
        float* op = out + ((size_t)((n*Ho+yo)*Wo + xo))*COUT + ob*TO;
        #pragma unroll
        for (int j4=0;j4<TO/4;j4++){
          float4 rr;
          rr.x = LRELU?lrelu_f(acc[g][py][px][j4*4+0]):acc[g][py][px][j4*4+0];
          rr.y = LRELU?lrelu_f(acc[g][py][px][j4*4+1]):acc[g][py][px][j4*4+1];
          rr.z = LRELU?lrelu_f(acc[g][py][px][j4*4+2]):acc[g][py][px][j4*4+2];
          rr.w = LRELU?lrelu_f(acc[g][py][px][j4*4+3]):acc[g][py][px][j4*4+3];
          *(float4*)(op+j4*4) = rr;
        }
      }
    }
  }
}

// ============ dec4: s1 deconv == 3x3 pad-1 conv, Cout=1; TX outputs share input columns ====
template<int H,int W,int CIN,int TX>
__global__ __launch_bounds__(256) void conv3x3_s1_co1_k(const float* __restrict__ in,
    const float* __restrict__ w, const float* __restrict__ bias, float* __restrict__ out,
    int total){
  constexpr int XB = W/TX;
  int t = blockIdx.x*256 + threadIdx.x;
  if (t >= total) return;
  int xb = t % XB; int p = t/XB;
  int y  = p % H;  int n = p/H;
  int x0 = xb*TX;

  float acc[TX];
  #pragma unroll
  for (int px=0;px<TX;px++) acc[px] = bias[0];

  #pragma unroll
  for (int ky=0;ky<3;ky++){
    int iy = y + ky - 1;
    if (iy < 0 || iy >= H) continue;
    const float* row = in + ((size_t)n*H + iy)*(size_t)(W*CIN);
    const float* wk  = w + (ky*3)*CIN;
    for (int c=0;c<CIN;c+=4){
      float4 wv[3];
      #pragma unroll
      for (int kx=0;kx<3;kx++) wv[kx] = *(const float4*)(wk + kx*CIN + c);
      #pragma unroll
      for (int j=0;j<TX+2;j++){
        int ix = x0 + j - 1;
        bool ok = (ix >= 0 && ix < W);
        float4 v = *(const float4*)(row + (size_t)(ok ? ix : 0)*CIN + c);
        if (!ok) v = zero4();
        #pragma unroll
        for (int kx=0;kx<3;kx++){
          int px = j - kx;
          if (px >= 0 && px < TX){
            acc[px] += v.x*wv[kx].x + v.y*wv[kx].y + v.z*wv[kx].z + v.w*wv[kx].w;
          }
        }
      }
    }
  }
  float* op = out + (size_t)(n*H + y)*W + x0;
  if constexpr (TX == 4){
    float4 r; r.x=acc[0]; r.y=acc[1]; r.z=acc[2]; r.w=acc[3];
    *(float4*)op = r;
  } else {
    #pragma unroll
    for (int px=0;px<TX;px++) op[px] = acc[px];
  }
}

extern "C" void kernel_launch(void* const* d_in, const int* in_sizes, int n_in,
                              void* d_out, int out_size, void* d_ws, size_t ws_size,
                              hipStream_t stream) {
  const float* x   = (const float*)d_in[0];
  const float* e1w = (const float*)d_in[1];  const float* e1b = (const float*)d_in[2];
  const float* e2w = (const float*)d_in[3];  const float* e2b = (const float*)d_in[4];
  const float* e3w = (const float*)d_in[5];  const float* e3b = (const float*)d_in[6];
  const float* e4w = (const float*)d_in[7];  const float* e4b = (const float*)d_in[8];
  const float* cb  = (const float*)d_in[9];
  const float* d1w = (const float*)d_in[10]; const float* d1b = (const float*)d_in[11];
  const float* d2w = (const float*)d_in[12]; const float* d2b = (const float*)d_in[13];
  const float* d3w = (const float*)d_in[14]; const float* d3b = (const float*)d_in[15];
  const float* d4w = (const float*)d_in[16]; const float* d4b = (const float*)d_in[17];
  float* out = (float*)d_out;

  // Per-image ping-pong: A = max(h1,h3,d1,d3) = 8 MiB/img; B = max(h2,q,d2) = 4 MiB/img.
  const size_t MiB = 1ull << 20;
  int Bc = 32;
  while (Bc > 1 && (size_t)Bc * 12 * MiB > ws_size) Bc >>= 1;

  char* wsb = (char*)d_ws;
  float* A  = (float*)wsb;                              // Bc * 8 MiB
  float* Bf = (float*)(wsb + (size_t)Bc * 8 * MiB);     // Bc * 4 MiB

  for (int n0 = 0; n0 < 32; n0 += Bc) {
    const float* xc = x   + (size_t)n0 * 256*256*3;
    float*      oc  = out + (size_t)n0 * 256*256;

    // enc1: [Bc,256,256,3] -> [Bc,128,128,32]; TO=8(OB=4), TX=2(XB=64)
    int t1 = Bc*128*64*4;
    conv3x3_s2_k<256,256,3,32,8,2,true><<<t1/256,256,0,stream>>>(xc, e1w, e1b, A, t1);
    // enc2: -> [Bc,64,64,64]; TO=8(OB=8), TX=4(XB=16)
    int t2 = Bc*64*16*8;
    conv3x3_s2_k<128,128,32,64,8,4,true><<<t2/256,256,0,stream>>>(A, e2w, e2b, Bf, t2);
    // enc3: -> [Bc,32,32,64]; TO=8(OB=8), TX=4(XB=8)
    int t3 = Bc*32*8*8;
    conv3x3_s2_k<64,64,64,64,8,4,true><<<t3/256,256,0,stream>>>(Bf, e3w, e3b, A, t3);
    // enc4 (1x1, 64->32) + VQ: -> q [Bc,32,32,32]
    int npix = Bc*32*32;
    enc4_vq_k<64,32,64><<<npix/256,256,0,stream>>>(A, e4w, e4b, cb, Bf, npix);
    // dec1: [Bc,32,32,32] -> [Bc,64,64,64]; TO=8(OB=8), TX=2(XB=16)
    int t5 = Bc*32*16*8;
    deconv3x3_s2_g_k<32,32,32,64,8,2,true><<<t5/256,256,0,stream>>>(Bf, d1w, d1b, A, t5);
    // dec2: -> [Bc,128,128,64]; TO=8(OB=8), TX=2(XB=32)
    int t6 = Bc*64*32*8;
    deconv3x3_s2_g_k<64,64,64,64,8,2,true><<<t6/256,256,0,stream>>>(A, d2w, d2b, Bf, t6);
    // dec3: -> [Bc,256,256,32]; TO=8(OB=4), TX=2(XB=64)
    int t7 = Bc*128*64*4;
    deconv3x3_s2_g_k<128,128,64,32,8,2,true><<<t7/256,256,0,stream>>>(Bf, d3w, d3b, A, t7);
    // dec4: -> [Bc,256,256,1]; TX=4
    int t8 = Bc*256*64;
    conv3x3_s1_co1_k<256,256,32,4><<<t8/256,256,0,stream>>>(A, d4w, d4b, oc, t8);
  }
}